// Round 1
// baseline (13318.271 us; speedup 1.0000x reference)
//
#include <hip/hip_runtime.h>
#include <cmath>

namespace {

constexpr int Dm  = 512;
constexpr int Bn  = 32;
constexpr int Lq  = 16;
constexpr int V1  = 8193;
constexpr int DFF = 2048;
constexpr int NL  = 2;

constexpr int NB  = 256;            // persistent blocks; all co-resident (1-2 per CU)
constexpr int NT  = 256;            // threads per block (4 waves)
constexpr int NW  = NB * 4;         // total waves = 1024
constexpr int ZTH = (NB - Bn) * NT; // idle-block zero-duty threads

struct Params {
  const int*   meanings;
  const float* emb;
  const float* v2e;
  const float* e2v_w; const float* e2v_b;
  const float* sa_qkv_w; const float* sa_qkv_b;
  const float* sa_out_w; const float* sa_out_b;
  const float* ca_qkv_w; const float* ca_qkv_b;
  const float* ca_out_w; const float* ca_out_b;
  const float* ffn_w1; const float* ffn_b1;
  const float* ffn_w2; const float* ffn_b2;
  const float* ln1_g; const float* ln1_b;
  const float* ln2_g; const float* ln2_b;
  const float* ln3_g; const float* ln3_b;
  unsigned* bar;
  float* src; float* tmpv; float* caC; float* x; float* q; float* aout; float* h1;
  float* kcache; float* vcache;
  float* outToks; float* outLogits;
};

__device__ __forceinline__ float wred(float v) {
#pragma unroll
  for (int off = 32; off; off >>= 1) v += __shfl_down(v, off, 64);
  return v;
}

__device__ __forceinline__ float dot4(const float4 w, const float4 x, float a) {
  a = fmaf(w.x, x.x, a); a = fmaf(w.y, x.y, a);
  a = fmaf(w.z, x.z, a); a = fmaf(w.w, x.w, a);
  return a;
}

__device__ __forceinline__ float pe_val(int pos, int t) {
  const int j2 = (t >> 1) << 1;
  const float div = expf((float)j2 * (-9.210340371976184f / 512.0f));
  const float ang = (float)pos * div;
  return (t & 1) ? cosf(ang) : sinf(ang);
}

__global__ __launch_bounds__(64) void init_bar(unsigned* bar) {
  if (threadIdx.x < 2) bar[threadIdx.x] = 0u;
}

// grid-wide barrier: generation counter, agent-scope atomics (coherent across XCDs)
__device__ void gsync(unsigned* bar) {
  __syncthreads();
  if (threadIdx.x == 0) {
    __threadfence();
    const unsigned g = __hip_atomic_load(bar + 1, __ATOMIC_RELAXED, __HIP_MEMORY_SCOPE_AGENT);
    const unsigned a = __hip_atomic_fetch_add(bar, 1u, __ATOMIC_ACQ_REL, __HIP_MEMORY_SCOPE_AGENT);
    if (a == (unsigned)(NB - 1)) {
      __hip_atomic_store(bar, 0u, __ATOMIC_RELAXED, __HIP_MEMORY_SCOPE_AGENT);
      __hip_atomic_fetch_add(bar + 1, 1u, __ATOMIC_RELEASE, __HIP_MEMORY_SCOPE_AGENT);
    } else {
      while (__hip_atomic_load(bar + 1, __ATOMIC_ACQUIRE, __HIP_MEMORY_SCOPE_AGENT) == g) {
        __builtin_amdgcn_s_sleep(1);
      }
    }
  }
  __syncthreads();
}

// idle blocks (bid >= Bn) zero a buffer consumed by next phase's atomics
__device__ __forceinline__ void zero_range(float* p, int n) {
  const int zid = ((int)blockIdx.x - Bn) * NT + (int)threadIdx.x;
  for (int idx = zid; idx < n; idx += ZTH) p[idx] = 0.f;
}

// stage x[32][512] into LDS, XOR-swizzled quads (kills b-major bank conflicts)
__device__ __forceinline__ void fg_stage(float* smem, const float* __restrict__ xsrc) {
  for (int idx = threadIdx.x; idx < 4096; idx += NT) {
    const int b = idx >> 7, q = idx & 127;
    const float4 v = *(const float4*)(xsrc + (b << 9) + (q << 2));
    *(float4*)(smem + (b << 9) + ((q ^ (b & 7)) << 2)) = v;
  }
  __syncthreads();
}

// full-grid matvec, K=512. lane=(b,nh); 4 rows/lane; each W quad read once,
// broadcast across the 32 b-lanes; FMA-bound inner loop.
template <int KS, bool ATOMIC>
__device__ __forceinline__ void fg_dense(const float* smem, const float* __restrict__ W,
                                         const float* __restrict__ bias, float* __restrict__ y,
                                         int ystride, int N) {
  constexpr int QC = 128 / KS;
  const int lane = (int)threadIdx.x & 63;
  const int gw = (int)blockIdx.x * 4 + ((int)threadIdx.x >> 6);
  const int bl = lane & 31, nh = lane >> 5, sw = bl & 7;
  const float* xb = smem + (bl << 9);
  const int njobs = (N >> 3) * KS;
  for (int jid = gw; jid < njobs; jid += NW) {
    const int rg = jid / KS, kc = jid - rg * KS;
    const int n0 = (rg << 3) + (nh << 2);
    const float* w = W + (size_t)n0 * Dm + ((kc * QC) << 2);
    float a0 = 0.f, a1 = 0.f, a2 = 0.f, a3 = 0.f;
#pragma unroll 4
    for (int qq = 0; qq < QC; ++qq) {
      const int q = kc * QC + qq;
      const float4 xv = *(const float4*)(xb + ((q ^ sw) << 2));
      const float* wq = w + (qq << 2);
      a0 = dot4(*(const float4*)(wq), xv, a0);
      a1 = dot4(*(const float4*)(wq + Dm), xv, a1);
      a2 = dot4(*(const float4*)(wq + 2 * Dm), xv, a2);
      a3 = dot4(*(const float4*)(wq + 3 * Dm), xv, a3);
    }
    float* yb = y + (size_t)bl * ystride + n0;
    if (ATOMIC) {
      if (kc == 0) { a0 += bias[n0]; a1 += bias[n0 + 1]; a2 += bias[n0 + 2]; a3 += bias[n0 + 3]; }
      atomicAdd(yb, a0); atomicAdd(yb + 1, a1); atomicAdd(yb + 2, a2); atomicAdd(yb + 3, a3);
    } else {
      yb[0] = a0 + bias[n0];     yb[1] = a1 + bias[n0 + 1];
      yb[2] = a2 + bias[n0 + 2]; yb[3] = a3 + bias[n0 + 3];
    }
  }
}

// QKV matvec with routing q/k/v (rows 0..511 / 512..1023 / 1024..1535)
__device__ __forceinline__ void fg_qkv(const float* smem, const float* __restrict__ W,
                                       const float* __restrict__ bias, float* __restrict__ qb,
                                       float* __restrict__ kslot, float* __restrict__ vslot) {
  constexpr int KS = 4, QC = 128 / KS;
  const int lane = (int)threadIdx.x & 63;
  const int gw = (int)blockIdx.x * 4 + ((int)threadIdx.x >> 6);
  const int bl = lane & 31, nh = lane >> 5, sw = bl & 7;
  const float* xb = smem + (bl << 9);
  constexpr int njobs = (3 * Dm / 8) * KS;  // 768
  for (int jid = gw; jid < njobs; jid += NW) {
    const int rg = jid / KS, kc = jid - rg * KS;
    const int n0 = (rg << 3) + (nh << 2);
    const float* w = W + (size_t)n0 * Dm + ((kc * QC) << 2);
    float a0 = 0.f, a1 = 0.f, a2 = 0.f, a3 = 0.f;
#pragma unroll 4
    for (int qq = 0; qq < QC; ++qq) {
      const int q = kc * QC + qq;
      const float4 xv = *(const float4*)(xb + ((q ^ sw) << 2));
      const float* wq = w + (qq << 2);
      a0 = dot4(*(const float4*)(wq), xv, a0);
      a1 = dot4(*(const float4*)(wq + Dm), xv, a1);
      a2 = dot4(*(const float4*)(wq + 2 * Dm), xv, a2);
      a3 = dot4(*(const float4*)(wq + 3 * Dm), xv, a3);
    }
    if (kc == 0) { a0 += bias[n0]; a1 += bias[n0 + 1]; a2 += bias[n0 + 2]; a3 += bias[n0 + 3]; }
    float* dst; int nn;
    if (n0 < Dm)          { dst = qb;    nn = n0; }
    else if (n0 < 2 * Dm) { dst = kslot; nn = n0 - Dm; }
    else                  { dst = vslot; nn = n0 - 2 * Dm; }
    float* yb = dst + (bl << 9) + nn;
    atomicAdd(yb, a0); atomicAdd(yb + 1, a1); atomicAdd(yb + 2, a2); atomicAdd(yb + 3, a3);
  }
}

__device__ __forceinline__ void block_ln(float* s, const float* __restrict__ g,
                                         const float* __restrict__ bb, float* red) {
  const int tid = (int)threadIdx.x;
  float ls = 0.f, lq = 0.f;
  for (int t = tid; t < Dm; t += NT) { const float v = s[t]; ls += v; lq += v * v; }
  ls = wred(ls); lq = wred(lq);
  const int wave = tid >> 6, lane = tid & 63;
  if (lane == 0) { red[wave] = ls; red[4 + wave] = lq; }
  __syncthreads();
  const float sum = red[0] + red[1] + red[2] + red[3];
  const float sq  = red[4] + red[5] + red[6] + red[7];
  const float mean = sum * (1.f / Dm);
  const float var  = sq * (1.f / Dm) - mean * mean;
  const float inv  = 1.f / sqrtf(var + 1e-5f);
  __syncthreads();
  for (int t = tid; t < Dm; t += NT) s[t] = (s[t] - mean) * inv * g[t] + bb[t];
}

__global__ __launch_bounds__(NT) void persist(Params p) {
  __shared__ float smem[16384];  // 64 KB, unioned across phases
  const int tid  = (int)threadIdx.x;
  const int bid  = (int)blockIdx.x;
  const int lane = tid & 63;
  const int wave = tid >> 6;
  const int gw   = bid * 4 + wave;

  // ---- S0: src[b][t] = sum_ty emb[meanings[b][ty]+32*ty][t]
  {
    const int gid = bid * NT + tid;
    if (gid < Bn * Dm) {
      const int b = gid >> 9, t = gid & 511;
      float s = 0.f;
#pragma unroll
      for (int ty = 0; ty < 8; ++ty) {
        const int m = p.meanings[b * 8 + ty] + ty * 32;
        s += p.emb[(size_t)m * Dm + t];
      }
      p.src[gid] = s;
    }
  }
  gsync(p.bar);

  // ---- cross-attn constants: caC[l] = Wo_l @ (Wv_l src + bv_l) + bo_l (memory len 1)
  for (int l = 0; l < NL; ++l) {
    if (bid * 4 < 64) fg_stage(smem, p.src);
    fg_dense<1, false>(smem, p.ca_qkv_w + ((size_t)l * 3 + 2) * Dm * Dm,
                       p.ca_qkv_b + l * 3 * Dm + 2 * Dm, p.tmpv, Dm, Dm);
    gsync(p.bar);
    if (bid * 4 < 64) fg_stage(smem, p.tmpv);
    fg_dense<1, false>(smem, p.ca_out_w + (size_t)l * Dm * Dm,
                       p.ca_out_b + l * Dm, p.caC + l * Bn * Dm, Dm, Dm);
    gsync(p.bar);
  }

  // ---- embed step 0 (start token), zero first qkv targets
  if (bid < Bn) {
    for (int t = tid; t < Dm; t += NT)
      p.x[(bid << 9) + t] = p.v2e[(size_t)(V1 - 1) * Dm + t] + pe_val(0, t);
  } else {
    zero_range(p.q, Bn * Dm);
    zero_range(p.kcache, Bn * Dm);
    zero_range(p.vcache, Bn * Dm);
  }
  gsync(p.bar);

  for (int i = 0; i < Lq; ++i) {
    for (int l = 0; l < NL; ++l) {
      float* kcl   = p.kcache + (size_t)l * Lq * Bn * Dm;
      float* vcl   = p.vcache + (size_t)l * Lq * Bn * Dm;
      float* kslot = kcl + (size_t)i * Bn * Dm;
      float* vslot = vcl + (size_t)i * Bn * Dm;

      // FG_QKV (atomic k-split into pre-zeroed q/kslot/vslot)
      if (bid * 4 < 768) fg_stage(smem, p.x);
      fg_qkv(smem, p.sa_qkv_w + (size_t)l * 3 * Dm * Dm, p.sa_qkv_b + l * 3 * Dm,
             p.q, kslot, vslot);
      gsync(p.bar);

      // PB_ATTN (one block per b); idle blocks zero tmpv for FG_OUT
      if (bid < Bn) {
        const int b = bid;
        for (int t = tid; t < Dm; t += NT) smem[t] = p.q[(b << 9) + t];
        __syncthreads();
        float* sS = smem + Dm;
        for (int j = wave; j <= i; j += 4) {
          const float* kr = kcl + ((size_t)(j * Bn + b) << 9);
          float acc = dot4(*(const float4*)(kr + (lane << 2)),
                           *(const float4*)(smem + (lane << 2)), 0.f);
          acc = dot4(*(const float4*)(kr + 256 + (lane << 2)),
                     *(const float4*)(smem + 256 + (lane << 2)), acc);
          acc = wred(acc);
          if (lane == 0) sS[j] = acc * 0.044194173824159216f;  // 1/sqrt(512)
        }
        __syncthreads();
        if (tid == 0) {
          float m = -1e30f;
          for (int j = 0; j <= i; ++j) m = fmaxf(m, sS[j]);
          float s = 0.f;
          for (int j = 0; j <= i; ++j) { const float e = expf(sS[j] - m); sS[j] = e; s += e; }
          const float inv = 1.f / s;
          for (int j = 0; j <= i; ++j) sS[j] *= inv;
        }
        __syncthreads();
        for (int t = tid; t < Dm; t += NT) {
          float acc = 0.f;
          for (int j = 0; j <= i; ++j) acc += sS[j] * vcl[((size_t)(j * Bn + b) << 9) + t];
          p.aout[(b << 9) + t] = acc;
        }
      } else {
        zero_range(p.tmpv, Bn * Dm);
      }
      gsync(p.bar);

      // FG_OUT -> tmpv (atomic, KS=8)
      if (bid * 4 < 512) fg_stage(smem, p.aout);
      fg_dense<8, true>(smem, p.sa_out_w + (size_t)l * Dm * Dm, p.sa_out_b + l * Dm,
                        p.tmpv, Dm, Dm);
      gsync(p.bar);

      // PB_LN12: x = LN2(LN1(x + sa) + ca); idle blocks zero h1 for FFN1
      if (bid < Bn) {
        float* sR = smem; float* red = smem + Dm;
        for (int t = tid; t < Dm; t += NT)
          sR[t] = p.x[(bid << 9) + t] + p.tmpv[(bid << 9) + t];
        __syncthreads();
        block_ln(sR, p.ln1_g + l * Dm, p.ln1_b + l * Dm, red);
        __syncthreads();
        for (int t = tid; t < Dm; t += NT)
          sR[t] += p.caC[l * Bn * Dm + (bid << 9) + t];
        __syncthreads();
        block_ln(sR, p.ln2_g + l * Dm, p.ln2_b + l * Dm, red);
        __syncthreads();
        for (int t = tid; t < Dm; t += NT) p.x[(bid << 9) + t] = sR[t];
      } else {
        zero_range(p.h1, Bn * DFF);
      }
      gsync(p.bar);

      // FG_FFN1 -> h1 pre-relu (atomic, KS=4); tail: zero tmpv for FFN2
      fg_stage(smem, p.x);
      fg_dense<4, true>(smem, p.ffn_w1 + (size_t)l * DFF * Dm, p.ffn_b1 + l * DFF,
                        p.h1, DFF, DFF);
      if (lane < 16) p.tmpv[(gw << 4) + lane] = 0.f;
      gsync(p.bar);

      // BL_FFN2: stage relu(h1) k-chunk per block, 8 rows/block, atomic into tmpv
      {
        const int kc2 = bid & 3, rgb = bid >> 2;
        for (int idx = tid; idx < 4096; idx += NT) {
          const int b = idx >> 7, qq = idx & 127;
          float4 v = *(const float4*)(p.h1 + (size_t)b * DFF + (kc2 << 9) + (qq << 2));
          v.x = fmaxf(v.x, 0.f); v.y = fmaxf(v.y, 0.f);
          v.z = fmaxf(v.z, 0.f); v.w = fmaxf(v.w, 0.f);
          *(float4*)(smem + (b << 9) + ((qq ^ (b & 7)) << 2)) = v;
        }
        __syncthreads();
        const int bl = lane & 31, nh = lane >> 5, sw = bl & 7;
        const int row = (rgb << 3) + (wave << 1) + nh;
        const float* w = p.ffn_w2 + (size_t)l * Dm * DFF + (size_t)row * DFF + (kc2 << 9);
        const float* xb = smem + (bl << 9);
        float a = 0.f;
#pragma unroll 4
        for (int qq = 0; qq < 128; ++qq) {
          a = dot4(*(const float4*)(w + (qq << 2)),
                   *(const float4*)(xb + ((qq ^ sw) << 2)), a);
        }
        if (kc2 == 0) a += p.ffn_b2[l * Dm + row];
        atomicAdd(p.tmpv + (bl << 9) + row, a);
      }
      gsync(p.bar);

      // PB_LN3: x = LN3(x + ff); idle blocks pre-zero next layer's qkv targets
      if (bid < Bn) {
        float* sR = smem; float* red = smem + Dm;
        for (int t = tid; t < Dm; t += NT)
          sR[t] = p.x[(bid << 9) + t] + p.tmpv[(bid << 9) + t];
        __syncthreads();
        block_ln(sR, p.ln3_g + l * Dm, p.ln3_b + l * Dm, red);
        __syncthreads();
        for (int t = tid; t < Dm; t += NT) p.x[(bid << 9) + t] = sR[t];
      } else if (l == 0) {
        zero_range(p.q, Bn * Dm);
        zero_range(p.kcache + ((size_t)Lq + i) * Bn * Dm, Bn * Dm);
        zero_range(p.vcache + ((size_t)Lq + i) * Bn * Dm, Bn * Dm);
      }
      gsync(p.bar);
    }  // l

    // FG_LOGITS rows 0..8191, direct write (row 8192 handled in PB_AE)
    fg_stage(smem, p.x);
    fg_dense<1, false>(smem, p.e2v_w, p.e2v_b,
                       p.outLogits + (size_t)i * Bn * V1, V1, 8192);
    gsync(p.bar);

    // PB_AE: logit row 8192 + argmax + next-token embed; idle zero next qkv
    if (bid < Bn) {
      const int b = bid;
      float ls = 0.f;
      for (int t = tid; t < Dm; t += NT)
        ls += p.x[(b << 9) + t] * p.e2v_w[(size_t)8192 * Dm + t];
      ls = wred(ls);
      float* red = smem;
      float* sv  = smem + 8;
      int*   si  = (int*)(smem + 8 + NT);
      if (lane == 0) red[wave] = ls;
      __syncthreads();
      if (tid == 0) {
        const float lg = red[0] + red[1] + red[2] + red[3] + p.e2v_b[8192];
        p.outLogits[((size_t)i * Bn + b) * V1 + 8192] = lg;
        red[4] = lg;
      }
      __syncthreads();
      const float lg = red[4];
      const float* row = p.outLogits + ((size_t)i * Bn + b) * V1;
      float best = -1e30f; int bi = 0;
      for (int v = tid; v < 8192; v += NT) {
        const float val = row[v];
        if (val > best) { best = val; bi = v; }  // strided ascending keeps first max
      }
      sv[tid] = best; si[tid] = bi;
      __syncthreads();
      for (int off = 128; off; off >>= 1) {
        if (tid < off) {
          const float v2 = sv[tid + off]; const int i2 = si[tid + off];
          if (v2 > sv[tid] || (v2 == sv[tid] && i2 < si[tid])) { sv[tid] = v2; si[tid] = i2; }
        }
        __syncthreads();
      }
      if (tid == 0) {
        int tok = si[0];
        if (lg > sv[0]) tok = 8192;  // last index: only on strictly greater
        p.outToks[i * Bn + b] = (float)tok;
        si[0] = tok;
      }
      __syncthreads();
      const int tok = si[0];
      if (i + 1 < Lq) {
        for (int t = tid; t < Dm; t += NT)
          p.x[(b << 9) + t] = p.v2e[(size_t)tok * Dm + t] + pe_val(i + 1, t);
      }
    } else {
      if (i + 1 < Lq) {
        zero_range(p.q, Bn * Dm);
        zero_range(p.kcache + (size_t)(i + 1) * Bn * Dm, Bn * Dm);
        zero_range(p.vcache + (size_t)(i + 1) * Bn * Dm, Bn * Dm);
      }
    }
    gsync(p.bar);
  }  // i
}

}  // namespace

extern "C" void kernel_launch(void* const* d_in, const int* in_sizes, int n_in,
                              void* d_out, int out_size, void* d_ws, size_t ws_size,
                              hipStream_t stream) {
  (void)in_sizes; (void)n_in; (void)out_size; (void)ws_size;
  char* ws = (char*)d_ws;

  Params p;
  p.meanings = (const int*)d_in[0];
  p.emb      = (const float*)d_in[1];
  p.v2e      = (const float*)d_in[2];
  p.e2v_w    = (const float*)d_in[3];
  p.e2v_b    = (const float*)d_in[4];
  p.sa_qkv_w = (const float*)d_in[5];
  p.sa_qkv_b = (const float*)d_in[6];
  p.sa_out_w = (const float*)d_in[7];
  p.sa_out_b = (const float*)d_in[8];
  p.ca_qkv_w = (const float*)d_in[9];
  p.ca_qkv_b = (const float*)d_in[10];
  p.ca_out_w = (const float*)d_in[11];
  p.ca_out_b = (const float*)d_in[12];
  p.ffn_w1   = (const float*)d_in[13];
  p.ffn_b1   = (const float*)d_in[14];
  p.ffn_w2   = (const float*)d_in[15];
  p.ffn_b2   = (const float*)d_in[16];
  p.ln1_g = (const float*)d_in[17]; p.ln1_b = (const float*)d_in[18];
  p.ln2_g = (const float*)d_in[19]; p.ln2_b = (const float*)d_in[20];
  p.ln3_g = (const float*)d_in[21]; p.ln3_b = (const float*)d_in[22];

  p.bar = (unsigned*)ws;
  float* f = (float*)(ws + 128);
  p.src  = f;  f += Bn * Dm;
  p.tmpv = f;  f += Bn * Dm;
  p.caC  = f;  f += NL * Bn * Dm;
  p.x    = f;  f += Bn * Dm;
  p.q    = f;  f += Bn * Dm;
  p.aout = f;  f += Bn * Dm;
  p.h1   = f;  f += Bn * DFF;
  p.kcache = f; f += (size_t)NL * Lq * Bn * Dm;
  p.vcache = f;

  p.outToks   = (float*)d_out;
  p.outLogits = (float*)d_out + Lq * Bn;

  init_bar<<<1, 64, 0, stream>>>(p.bar);
  persist<<<NB, NT, 0, stream>>>(p);
}

// Round 3
// 5246.323 us; speedup vs baseline: 2.5386x; 2.5386x over previous
//
#include <hip/hip_runtime.h>
#include <cmath>

namespace {

constexpr int Dm  = 512;
constexpr int Bn  = 32;
constexpr int Lq  = 16;
constexpr int V1  = 8193;
constexpr int DFF = 2048;
constexpr int NL  = 2;
constexpr int NT  = 256;

__device__ __forceinline__ float wred(float v) {
#pragma unroll
  for (int off = 32; off; off >>= 1) v += __shfl_down(v, off, 64);
  return v;
}

__device__ __forceinline__ float dot4(const float4 w, const float4 x, float a) {
  a = fmaf(w.x, x.x, a); a = fmaf(w.y, x.y, a);
  a = fmaf(w.z, x.z, a); a = fmaf(w.w, x.w, a);
  return a;
}

__device__ __forceinline__ float pe_val(int pos, int t) {
  const int j2 = (t >> 1) << 1;
  const float div = expf((float)j2 * (-9.210340371976184f / 512.0f));
  const float ang = (float)pos * div;
  return (t & 1) ? cosf(ang) : sinf(ang);
}

// stage x[32][512] into LDS (16384 floats = 64 KB), XOR-swizzled quads
// (kills b-major bank conflicts on the broadcast read)
__device__ __forceinline__ void fg_stage(float* smem, const float* __restrict__ xsrc) {
#pragma unroll
  for (int idx = threadIdx.x; idx < 4096; idx += NT) {
    const int b = idx >> 7, q = idx & 127;
    const float4 v = *(const float4*)(xsrc + (b << 9) + (q << 2));
    *(float4*)(smem + (b << 9) + ((q ^ (b & 7)) << 2)) = v;
  }
  __syncthreads();
}

// batch-amortized rows: one wave = 8 output rows x all 32 batch elems;
// weights read once. lanes = 32 b x 2 row-halves; K = 512 staged in LDS.
__device__ __forceinline__ void fg_rows(const float* smem, const float* __restrict__ W,
                                        int rowStride, const float* __restrict__ bias,
                                        float* __restrict__ y, int ystride, int njobs) {
  const int lane = (int)threadIdx.x & 63;
  const int gw = (int)blockIdx.x * 4 + ((int)threadIdx.x >> 6);
  const int bl = lane & 31, nh = lane >> 5, sw = bl & 7;
  const float* xb = smem + (bl << 9);
  const int stride = (int)gridDim.x * 4;
  for (int jid = gw; jid < njobs; jid += stride) {
    const int n0 = (jid << 3) + (nh << 2);
    const float* w = W + (size_t)n0 * rowStride;
    float a0 = 0.f, a1 = 0.f, a2 = 0.f, a3 = 0.f;
#pragma unroll 4
    for (int qq = 0; qq < 128; ++qq) {
      const float4 xv = *(const float4*)(xb + ((qq ^ sw) << 2));
      const float* wq = w + (qq << 2);
      a0 = dot4(*(const float4*)(wq), xv, a0);
      a1 = dot4(*(const float4*)(wq + rowStride), xv, a1);
      a2 = dot4(*(const float4*)(wq + 2 * rowStride), xv, a2);
      a3 = dot4(*(const float4*)(wq + 3 * rowStride), xv, a3);
    }
    float* yb = y + (size_t)bl * ystride + n0;
    yb[0] = a0 + bias[n0];     yb[1] = a1 + bias[n0 + 1];
    yb[2] = a2 + bias[n0 + 2]; yb[3] = a3 + bias[n0 + 3];
  }
}

__global__ __launch_bounds__(NT) void fg_matvec(const float* __restrict__ x,
    const float* __restrict__ W, const float* __restrict__ bias,
    float* __restrict__ y, int ystride, int N) {
  __shared__ float smem[16384];  // 64 KB: full x[32][512] tile
  fg_stage(smem, x);
  fg_rows(smem, W, Dm, bias, y, ystride, N >> 3);
}

// QKV with routing q / kslot / vslot (rows 0..511 / 512..1023 / 1024..1535)
__global__ __launch_bounds__(NT) void fg_qkv(const float* __restrict__ x,
    const float* __restrict__ W, const float* __restrict__ bias,
    float* __restrict__ q, float* __restrict__ kslot, float* __restrict__ vslot) {
  __shared__ float smem[16384];  // 64 KB
  fg_stage(smem, x);
  const int lane = (int)threadIdx.x & 63;
  const int gw = (int)blockIdx.x * 4 + ((int)threadIdx.x >> 6);
  const int bl = lane & 31, nh = lane >> 5, sw = bl & 7;
  const float* xb = smem + (bl << 9);
  const int stride = (int)gridDim.x * 4;
  for (int jid = gw; jid < 192; jid += stride) {
    const int n0 = (jid << 3) + (nh << 2);
    const float* w = W + (size_t)n0 * Dm;
    float a0 = 0.f, a1 = 0.f, a2 = 0.f, a3 = 0.f;
#pragma unroll 4
    for (int qq = 0; qq < 128; ++qq) {
      const float4 xv = *(const float4*)(xb + ((qq ^ sw) << 2));
      const float* wq = w + (qq << 2);
      a0 = dot4(*(const float4*)(wq), xv, a0);
      a1 = dot4(*(const float4*)(wq + Dm), xv, a1);
      a2 = dot4(*(const float4*)(wq + 2 * Dm), xv, a2);
      a3 = dot4(*(const float4*)(wq + 3 * Dm), xv, a3);
    }
    a0 += bias[n0]; a1 += bias[n0 + 1]; a2 += bias[n0 + 2]; a3 += bias[n0 + 3];
    float* dst; int nn;
    if (n0 < Dm)          { dst = q;     nn = n0; }
    else if (n0 < 2 * Dm) { dst = kslot; nn = n0 - Dm; }
    else                  { dst = vslot; nn = n0 - 2 * Dm; }
    float* yb = dst + (bl << 9) + nn;
    yb[0] = a0; yb[1] = a1; yb[2] = a2; yb[3] = a3;
  }
}

// FFN2: K=2048 split in 4 chunks of 512; block stages relu(h1 chunk), writes
// partial[kc]; grid 64 = 16 row-groups x 4 kc; bias added in ln3red.
__global__ __launch_bounds__(NT) void fg_ffn2(const float* __restrict__ h1,
    const float* __restrict__ W, float* __restrict__ part) {
  __shared__ float smem[16384];  // 64 KB: relu(h1) chunk [32][512]
  const int kc = (int)blockIdx.x & 3;
#pragma unroll
  for (int idx = threadIdx.x; idx < 4096; idx += NT) {
    const int b = idx >> 7, q = idx & 127;
    float4 v = *(const float4*)(h1 + (size_t)b * DFF + (kc << 9) + (q << 2));
    v.x = fmaxf(v.x, 0.f); v.y = fmaxf(v.y, 0.f);
    v.z = fmaxf(v.z, 0.f); v.w = fmaxf(v.w, 0.f);
    *(float4*)(smem + (b << 9) + ((q ^ (b & 7)) << 2)) = v;
  }
  __syncthreads();
  const int lane = (int)threadIdx.x & 63;
  const int bl = lane & 31, nh = lane >> 5, sw = bl & 7;
  const float* xb = smem + (bl << 9);
  const int jid = ((int)blockIdx.x >> 2) * 4 + ((int)threadIdx.x >> 6);  // 0..63
  const int n0 = (jid << 3) + (nh << 2);
  const float* w = W + (size_t)n0 * DFF + (kc << 9);
  float a0 = 0.f, a1 = 0.f, a2 = 0.f, a3 = 0.f;
#pragma unroll 4
  for (int qq = 0; qq < 128; ++qq) {
    const float4 xv = *(const float4*)(xb + ((qq ^ sw) << 2));
    const float* wq = w + (qq << 2);
    a0 = dot4(*(const float4*)(wq), xv, a0);
    a1 = dot4(*(const float4*)(wq + DFF), xv, a1);
    a2 = dot4(*(const float4*)(wq + 2 * DFF), xv, a2);
    a3 = dot4(*(const float4*)(wq + 3 * DFF), xv, a3);
  }
  float* yb = part + (((size_t)kc * Bn + bl) << 9) + n0;
  yb[0] = a0; yb[1] = a1; yb[2] = a2; yb[3] = a3;
}

__device__ __forceinline__ void block_ln(float* s, const float* __restrict__ g,
                                         const float* __restrict__ bb, float* red) {
  const int tid = (int)threadIdx.x;
  float ls = 0.f, lq = 0.f;
  for (int t = tid; t < Dm; t += NT) { const float v = s[t]; ls += v; lq += v * v; }
  ls = wred(ls); lq = wred(lq);
  const int wave = tid >> 6, lane = tid & 63;
  if (lane == 0) { red[wave] = ls; red[4 + wave] = lq; }
  __syncthreads();
  const float sum = red[0] + red[1] + red[2] + red[3];
  const float sq  = red[4] + red[5] + red[6] + red[7];
  const float mean = sum * (1.f / Dm);
  const float var  = sq * (1.f / Dm) - mean * mean;
  const float inv  = 1.f / sqrtf(var + 1e-5f);
  __syncthreads();
  for (int t = tid; t < Dm; t += NT) s[t] = (s[t] - mean) * inv * g[t] + bb[t];
}

__global__ __launch_bounds__(NT) void attn_core(const float* __restrict__ q,
    const float* __restrict__ kc, const float* __restrict__ vc,
    float* __restrict__ aout, int pos) {
  __shared__ float sQ[Dm], sS[Lq];
  const int b = blockIdx.x, tid = threadIdx.x, lane = tid & 63, wave = tid >> 6;
  for (int t = tid; t < Dm; t += NT) sQ[t] = q[(b << 9) + t];
  __syncthreads();
  for (int j = wave; j <= pos; j += 4) {
    const float* kr = kc + ((size_t)(j * Bn + b) << 9);
    float acc = dot4(*(const float4*)(kr + (lane << 2)),
                     *(const float4*)(sQ + (lane << 2)), 0.f);
    acc = dot4(*(const float4*)(kr + 256 + (lane << 2)),
               *(const float4*)(sQ + 256 + (lane << 2)), acc);
    acc = wred(acc);
    if (lane == 0) sS[j] = acc * 0.044194173824159216f;  // 1/sqrt(512)
  }
  __syncthreads();
  if (tid == 0) {
    float m = -1e30f;
    for (int j = 0; j <= pos; ++j) m = fmaxf(m, sS[j]);
    float s = 0.f;
    for (int j = 0; j <= pos; ++j) { const float e = expf(sS[j] - m); sS[j] = e; s += e; }
    const float inv = 1.f / s;
    for (int j = 0; j <= pos; ++j) sS[j] *= inv;
  }
  __syncthreads();
  for (int t = tid; t < Dm; t += NT) {
    float acc = 0.f;
    for (int j = 0; j <= pos; ++j) acc += sS[j] * vc[((size_t)(j * Bn + b) << 9) + t];
    aout[(b << 9) + t] = acc;
  }
}

__global__ __launch_bounds__(NT) void ln12(const float* __restrict__ tmp,
    const float* __restrict__ ca,
    const float* __restrict__ g1, const float* __restrict__ b1,
    const float* __restrict__ g2, const float* __restrict__ b2,
    float* __restrict__ x) {
  __shared__ float sR[Dm], red[8];
  const int b = blockIdx.x, tid = threadIdx.x;
  for (int t = tid; t < Dm; t += NT) sR[t] = x[(b << 9) + t] + tmp[(b << 9) + t];
  __syncthreads();
  block_ln(sR, g1, b1, red);
  __syncthreads();
  for (int t = tid; t < Dm; t += NT) sR[t] += ca[(b << 9) + t];
  __syncthreads();
  block_ln(sR, g2, b2, red);
  __syncthreads();
  for (int t = tid; t < Dm; t += NT) x[(b << 9) + t] = sR[t];
}

// x = LN3(x + sum_kc part[kc] + b2)
__global__ __launch_bounds__(NT) void ln3red(const float* __restrict__ part,
    const float* __restrict__ b2,
    const float* __restrict__ g3, const float* __restrict__ bb3,
    float* __restrict__ x) {
  __shared__ float sR[Dm], red[8];
  const int b = blockIdx.x, tid = threadIdx.x;
  for (int t = tid; t < Dm; t += NT) {
    float v = x[(b << 9) + t] + b2[t];
#pragma unroll
    for (int kc = 0; kc < 4; ++kc) v += part[(((size_t)kc * Bn + b) << 9) + t];
    sR[t] = v;
  }
  __syncthreads();
  block_ln(sR, g3, bb3, red);
  __syncthreads();
  for (int t = tid; t < Dm; t += NT) x[(b << 9) + t] = sR[t];
}

__global__ __launch_bounds__(512) void src_kernel(const int* __restrict__ meanings,
                                                  const float* __restrict__ emb,
                                                  float* __restrict__ src) {
  const int b = blockIdx.x, t = threadIdx.x;
  float s = 0.f;
#pragma unroll
  for (int ty = 0; ty < 8; ++ty) {
    const int idx = meanings[b * 8 + ty] + ty * 32;
    s += emb[(size_t)idx * Dm + t];
  }
  src[b * Dm + t] = s;
}

__global__ __launch_bounds__(512) void embed0(const float* __restrict__ v2e,
                                              float* __restrict__ x) {
  const int b = blockIdx.x, t = threadIdx.x;
  x[(b << 9) + t] = v2e[(size_t)(V1 - 1) * Dm + t] + pe_val(0, t);
}

// logit row 8192 + argmax over 8193 + next-token embed (no token buffer)
__global__ __launch_bounds__(NT) void argmax_embed(float* __restrict__ x,
    const float* __restrict__ e2v_w, const float* __restrict__ e2v_b,
    const float* __restrict__ v2e, float* __restrict__ outLogits,
    float* __restrict__ outToks, int i) {
  __shared__ float red[8];
  __shared__ float sv[NT];
  __shared__ int   si[NT];
  const int b = blockIdx.x, tid = threadIdx.x, lane = tid & 63, wave = tid >> 6;
  float ls = 0.f;
  for (int t = tid; t < Dm; t += NT) ls += x[(b << 9) + t] * e2v_w[(size_t)8192 * Dm + t];
  ls = wred(ls);
  if (lane == 0) red[wave] = ls;
  __syncthreads();
  float* row = outLogits + ((size_t)i * Bn + b) * V1;
  if (tid == 0) {
    const float lg = red[0] + red[1] + red[2] + red[3] + e2v_b[8192];
    row[8192] = lg;
    red[4] = lg;
  }
  __syncthreads();
  const float lg = red[4];
  float best = -1e30f; int bi = 0;
  for (int v = tid; v < 8192; v += NT) {
    const float val = row[v];
    if (val > best) { best = val; bi = v; }  // strided ascending keeps first max
  }
  sv[tid] = best; si[tid] = bi;
  __syncthreads();
  for (int off = 128; off; off >>= 1) {
    if (tid < off) {
      const float v2 = sv[tid + off]; const int i2 = si[tid + off];
      if (v2 > sv[tid] || (v2 == sv[tid] && i2 < si[tid])) { sv[tid] = v2; si[tid] = i2; }
    }
    __syncthreads();
  }
  if (tid == 0) {
    int tok = si[0];
    if (lg > sv[0]) tok = 8192;  // last index wins only on strictly greater
    outToks[i * Bn + b] = (float)tok;
    si[0] = tok;
  }
  __syncthreads();
  const int tok = si[0];
  if (i + 1 < Lq) {
    for (int t = tid; t < Dm; t += NT)
      x[(b << 9) + t] = v2e[(size_t)tok * Dm + t] + pe_val(i + 1, t);
  }
}

}  // namespace

extern "C" void kernel_launch(void* const* d_in, const int* in_sizes, int n_in,
                              void* d_out, int out_size, void* d_ws, size_t ws_size,
                              hipStream_t stream) {
  (void)in_sizes; (void)n_in; (void)out_size; (void)ws_size;
  const int*   meanings  = (const int*)d_in[0];
  const float* emb_table = (const float*)d_in[1];
  const float* v2e_w     = (const float*)d_in[2];
  const float* e2v_w     = (const float*)d_in[3];
  const float* e2v_b     = (const float*)d_in[4];
  const float* sa_qkv_w  = (const float*)d_in[5];
  const float* sa_qkv_b  = (const float*)d_in[6];
  const float* sa_out_w  = (const float*)d_in[7];
  const float* sa_out_b  = (const float*)d_in[8];
  const float* ca_qkv_w  = (const float*)d_in[9];
  const float* ca_qkv_b  = (const float*)d_in[10];
  const float* ca_out_w  = (const float*)d_in[11];
  const float* ca_out_b  = (const float*)d_in[12];
  const float* ffn_w1    = (const float*)d_in[13];
  const float* ffn_b1    = (const float*)d_in[14];
  const float* ffn_w2    = (const float*)d_in[15];
  const float* ffn_b2    = (const float*)d_in[16];
  const float* ln1_g     = (const float*)d_in[17];
  const float* ln1_b     = (const float*)d_in[18];
  const float* ln2_g     = (const float*)d_in[19];
  const float* ln2_b     = (const float*)d_in[20];
  const float* ln3_g     = (const float*)d_in[21];
  const float* ln3_b     = (const float*)d_in[22];

  float* out = (float*)d_out;            // toks [16,32] then logits [16,32,8193]
  float* outLogits = out + Lq * Bn;

  float* f = (float*)d_ws;
  float* src  = f;  f += Bn * Dm;
  float* tmpv = f;  f += Bn * Dm;
  float* caC  = f;  f += NL * Bn * Dm;
  float* x    = f;  f += Bn * Dm;
  float* q    = f;  f += Bn * Dm;
  float* aout = f;  f += Bn * Dm;
  float* h1   = f;  f += Bn * DFF;
  float* part = f;  f += 4 * Bn * Dm;
  float* kcache = f; f += (size_t)NL * Lq * Bn * Dm;
  float* vcache = f;

  src_kernel<<<Bn, 512, 0, stream>>>(meanings, emb_table, src);

  // cross-attn constant per layer: caC[l] = Wo_l @ (Wv_l src + bv_l) + bo_l
  for (int l = 0; l < NL; ++l) {
    fg_matvec<<<16, NT, 0, stream>>>(src,
        ca_qkv_w + ((size_t)l * 3 + 2) * Dm * Dm, ca_qkv_b + l * 3 * Dm + 2 * Dm,
        tmpv, Dm, Dm);
    fg_matvec<<<16, NT, 0, stream>>>(tmpv,
        ca_out_w + (size_t)l * Dm * Dm, ca_out_b + l * Dm,
        caC + (size_t)l * Bn * Dm, Dm, Dm);
  }

  embed0<<<Bn, 512, 0, stream>>>(v2e_w, x);

  for (int i = 0; i < Lq; ++i) {
    for (int l = 0; l < NL; ++l) {
      float* kcl = kcache + (size_t)l * Lq * Bn * Dm;
      float* vcl = vcache + (size_t)l * Lq * Bn * Dm;
      fg_qkv<<<48, NT, 0, stream>>>(x,
          sa_qkv_w + (size_t)l * 3 * Dm * Dm, sa_qkv_b + l * 3 * Dm,
          q, kcl + (size_t)i * Bn * Dm, vcl + (size_t)i * Bn * Dm);
      attn_core<<<Bn, NT, 0, stream>>>(q, kcl, vcl, aout, i);
      fg_matvec<<<16, NT, 0, stream>>>(aout,
          sa_out_w + (size_t)l * Dm * Dm, sa_out_b + l * Dm, tmpv, Dm, Dm);
      ln12<<<Bn, NT, 0, stream>>>(tmpv, caC + (size_t)l * Bn * Dm,
          ln1_g + l * Dm, ln1_b + l * Dm, ln2_g + l * Dm, ln2_b + l * Dm, x);
      fg_matvec<<<64, NT, 0, stream>>>(x,
          ffn_w1 + (size_t)l * DFF * Dm, ffn_b1 + l * DFF, h1, DFF, DFF);
      fg_ffn2<<<64, NT, 0, stream>>>(h1, ffn_w2 + (size_t)l * Dm * DFF, part);
      ln3red<<<Bn, NT, 0, stream>>>(part, ffn_b2 + l * Dm,
          ln3_g + l * Dm, ln3_b + l * Dm, x);
    }
    fg_matvec<<<256, NT, 0, stream>>>(x, e2v_w, e2v_b,
        outLogits + (size_t)i * Bn * V1, V1, 8192);
    argmax_embed<<<Bn, NT, 0, stream>>>(x, e2v_w, e2v_b, v2e_w,
        outLogits, out, i);
  }
}

// Round 4
// 2736.460 us; speedup vs baseline: 4.8670x; 1.9172x over previous
//
#include <hip/hip_runtime.h>
#include <cmath>

namespace {

constexpr int Dm  = 512;
constexpr int Bn  = 32;
constexpr int Lq  = 16;
constexpr int V1  = 8193;
constexpr int DFF = 2048;
constexpr int NL  = 2;
constexpr int NT  = 256;

__device__ __forceinline__ float wred(float v) {
#pragma unroll
  for (int off = 32; off; off >>= 1) v += __shfl_down(v, off, 64);
  return v;
}

__device__ __forceinline__ float dot4(const float4 w, const float4 x, float a) {
  a = fmaf(w.x, x.x, a); a = fmaf(w.y, x.y, a);
  a = fmaf(w.z, x.z, a); a = fmaf(w.w, x.w, a);
  return a;
}

__device__ __forceinline__ float pe_val(int pos, int t) {
  const int j2 = (t >> 1) << 1;
  const float div = expf((float)j2 * (-9.210340371976184f / 512.0f));
  const float ang = (float)pos * div;
  return (t & 1) ? cosf(ang) : sinf(ang);
}

// ---- k-chunked batch-amortized GEMM producing partials -------------------
// grid = KS * (N/32) blocks, 256 thr. Block: kc = bx % KS, stages x[32][Kc]
// (summing SP source partials, optional relu), 4 waves each compute 8 rows
// x 32 batch over the chunk, write part[kc][32][N]. Bias added at kc==0.
template <int KS, int Kc, int SP, bool RELU>
__global__ __launch_bounds__(NT) void fg_part(
    const float* __restrict__ xsrc, int xstride, int srcPartStride,
    const float* __restrict__ W, int K,
    const float* __restrict__ bias,
    float* __restrict__ part, int N) {
  constexpr int QR = Kc / 4;  // quads per row
  __shared__ float smem[32 * Kc];
  const int kc = (int)blockIdx.x % KS;
  const int k0 = kc * Kc;
  for (int idx = threadIdx.x; idx < 8 * Kc; idx += NT) {
    const int b = idx / QR, q = idx - b * QR;
    const float* s0 = xsrc + (size_t)b * xstride + k0 + (q << 2);
    float4 v = *(const float4*)(s0);
#pragma unroll
    for (int s = 1; s < SP; ++s) {
      const float4 u = *(const float4*)(s0 + (size_t)s * srcPartStride);
      v.x += u.x; v.y += u.y; v.z += u.z; v.w += u.w;
    }
    if (RELU) {
      v.x = fmaxf(v.x, 0.f); v.y = fmaxf(v.y, 0.f);
      v.z = fmaxf(v.z, 0.f); v.w = fmaxf(v.w, 0.f);
    }
    *(float4*)(smem + b * Kc + ((q ^ (b & 7)) << 2)) = v;
  }
  __syncthreads();
  const int lane = (int)threadIdx.x & 63, wave = (int)threadIdx.x >> 6;
  const int bl = lane & 31, nh = lane >> 5, sw = bl & 7;
  const int rowjob = ((int)blockIdx.x / KS) * 4 + wave;
  const int n0 = (rowjob << 3) + (nh << 2);
  const float* xb = smem + bl * Kc;
  const float* w = W + (size_t)n0 * K + k0;
  float a0 = 0.f, a1 = 0.f, a2 = 0.f, a3 = 0.f;
#pragma unroll 4
  for (int qq = 0; qq < QR; ++qq) {
    const float4 xv = *(const float4*)(xb + ((qq ^ sw) << 2));
    const float* wq = w + (qq << 2);
    a0 = dot4(*(const float4*)(wq), xv, a0);
    a1 = dot4(*(const float4*)(wq + K), xv, a1);
    a2 = dot4(*(const float4*)(wq + 2 * K), xv, a2);
    a3 = dot4(*(const float4*)(wq + 3 * K), xv, a3);
  }
  if (kc == 0) {
    a0 += bias[n0]; a1 += bias[n0 + 1]; a2 += bias[n0 + 2]; a3 += bias[n0 + 3];
  }
  float* yb = part + (size_t)kc * 32 * N + (size_t)bl * N + n0;
  yb[0] = a0; yb[1] = a1; yb[2] = a2; yb[3] = a3;
}

// QKV variant: N=1536, K=512, KS=4, Kc=128; routes thirds into
// qkvp = [3 segs][4 kc][32][512]. grid 192.
__global__ __launch_bounds__(NT) void fg_qkv_part(const float* __restrict__ x,
    const float* __restrict__ W, const float* __restrict__ bias,
    float* __restrict__ qkvp) {
  constexpr int Kc = 128, QR = 32;
  __shared__ float smem[32 * Kc];
  const int kc = (int)blockIdx.x & 3;
  const int k0 = kc * Kc;
  for (int idx = threadIdx.x; idx < 8 * Kc; idx += NT) {
    const int b = idx / QR, q = idx - b * QR;
    const float4 v = *(const float4*)(x + (b << 9) + k0 + (q << 2));
    *(float4*)(smem + b * Kc + ((q ^ (b & 7)) << 2)) = v;
  }
  __syncthreads();
  const int lane = (int)threadIdx.x & 63, wave = (int)threadIdx.x >> 6;
  const int bl = lane & 31, nh = lane >> 5, sw = bl & 7;
  const int rowjob = ((int)blockIdx.x >> 2) * 4 + wave;  // 0..191
  const int n0 = (rowjob << 3) + (nh << 2);              // 0..1535
  const float* xb = smem + bl * Kc;
  const float* w = W + (size_t)n0 * Dm + k0;
  float a0 = 0.f, a1 = 0.f, a2 = 0.f, a3 = 0.f;
#pragma unroll 4
  for (int qq = 0; qq < QR; ++qq) {
    const float4 xv = *(const float4*)(xb + ((qq ^ sw) << 2));
    const float* wq = w + (qq << 2);
    a0 = dot4(*(const float4*)(wq), xv, a0);
    a1 = dot4(*(const float4*)(wq + Dm), xv, a1);
    a2 = dot4(*(const float4*)(wq + 2 * Dm), xv, a2);
    a3 = dot4(*(const float4*)(wq + 3 * Dm), xv, a3);
  }
  if (kc == 0) {
    a0 += bias[n0]; a1 += bias[n0 + 1]; a2 += bias[n0 + 2]; a3 += bias[n0 + 3];
  }
  const int seg = n0 >> 9;  // 0=q 1=k 2=v
  float* yb = qkvp + (size_t)seg * 65536 + (size_t)kc * 16384 + (bl << 9) + (n0 & 511);
  yb[0] = a0; yb[1] = a1; yb[2] = a2; yb[3] = a3;
}

__device__ __forceinline__ void block_ln(float* s, const float* __restrict__ g,
                                         const float* __restrict__ bb, float* red) {
  const int tid = (int)threadIdx.x;
  float ls = 0.f, lq = 0.f;
  for (int t = tid; t < Dm; t += NT) { const float v = s[t]; ls += v; lq += v * v; }
  ls = wred(ls); lq = wred(lq);
  const int wave = tid >> 6, lane = tid & 63;
  if (lane == 0) { red[wave] = ls; red[4 + wave] = lq; }
  __syncthreads();
  const float sum = red[0] + red[1] + red[2] + red[3];
  const float sq  = red[4] + red[5] + red[6] + red[7];
  const float mean = sum * (1.f / Dm);
  const float var  = sq * (1.f / Dm) - mean * mean;
  const float inv  = 1.f / sqrtf(var + 1e-5f);
  __syncthreads();
  for (int t = tid; t < Dm; t += NT) s[t] = (s[t] - mean) * inv * g[t] + bb[t];
}

// reduce qkv partials, finalize k/v cache slot, scores+softmax+PV
__global__ __launch_bounds__(NT) void attn_core(const float* __restrict__ qkvp,
    float* __restrict__ kcl, float* __restrict__ vcl,
    float* __restrict__ aout, int pos) {
  __shared__ float sQ[Dm], sK[Dm], sV[Dm], sS[Lq];
  const int b = blockIdx.x, tid = threadIdx.x, lane = tid & 63, wave = tid >> 6;
  const float* qp = qkvp;
  const float* kp = qkvp + 65536;
  const float* vp = qkvp + 131072;
  for (int t = tid; t < Dm; t += NT) {
    const int o = (b << 9) + t;
    const float qv = qp[o] + qp[o + 16384] + qp[o + 32768] + qp[o + 49152];
    const float kv = kp[o] + kp[o + 16384] + kp[o + 32768] + kp[o + 49152];
    const float vv = vp[o] + vp[o + 16384] + vp[o + 32768] + vp[o + 49152];
    sQ[t] = qv; sK[t] = kv; sV[t] = vv;
    const int co = ((pos * Bn + b) << 9) + t;
    kcl[co] = kv; vcl[co] = vv;
  }
  __syncthreads();
  for (int j = wave; j <= pos; j += 4) {
    float acc;
    if (j == pos) {
      acc = dot4(*(const float4*)(sK + (lane << 2)),
                 *(const float4*)(sQ + (lane << 2)), 0.f);
      acc = dot4(*(const float4*)(sK + 256 + (lane << 2)),
                 *(const float4*)(sQ + 256 + (lane << 2)), acc);
    } else {
      const float* kr = kcl + ((size_t)(j * Bn + b) << 9);
      acc = dot4(*(const float4*)(kr + (lane << 2)),
                 *(const float4*)(sQ + (lane << 2)), 0.f);
      acc = dot4(*(const float4*)(kr + 256 + (lane << 2)),
                 *(const float4*)(sQ + 256 + (lane << 2)), acc);
    }
    acc = wred(acc);
    if (lane == 0) sS[j] = acc * 0.044194173824159216f;  // 1/sqrt(512)
  }
  __syncthreads();
  if (tid == 0) {
    float m = -1e30f;
    for (int j = 0; j <= pos; ++j) m = fmaxf(m, sS[j]);
    float s = 0.f;
    for (int j = 0; j <= pos; ++j) { const float e = expf(sS[j] - m); sS[j] = e; s += e; }
    const float inv = 1.f / s;
    for (int j = 0; j <= pos; ++j) sS[j] *= inv;
  }
  __syncthreads();
  for (int t = tid; t < Dm; t += NT) {
    float acc = sS[pos] * sV[t];
    for (int j = 0; j < pos; ++j) acc += sS[j] * vcl[((size_t)(j * Bn + b) << 9) + t];
    aout[(b << 9) + t] = acc;
  }
}

// x = LN2(LN1(x + sum sop parts) + sum caCp parts)
__global__ __launch_bounds__(NT) void ln12(const float* __restrict__ sop,
    const float* __restrict__ caCp,
    const float* __restrict__ g1, const float* __restrict__ b1,
    const float* __restrict__ g2, const float* __restrict__ b2,
    float* __restrict__ x) {
  __shared__ float sR[Dm], red[8];
  const int b = blockIdx.x, tid = threadIdx.x;
  for (int t = tid; t < Dm; t += NT) {
    const int o = (b << 9) + t;
    sR[t] = x[o] + sop[o] + sop[o + 16384] + sop[o + 32768] + sop[o + 49152];
  }
  __syncthreads();
  block_ln(sR, g1, b1, red);
  __syncthreads();
  for (int t = tid; t < Dm; t += NT) {
    const int o = (b << 9) + t;
    sR[t] += caCp[o] + caCp[o + 16384] + caCp[o + 32768] + caCp[o + 49152];
  }
  __syncthreads();
  block_ln(sR, g2, b2, red);
  __syncthreads();
  for (int t = tid; t < Dm; t += NT) x[(b << 9) + t] = sR[t];
}

// x = LN3(x + sum of 8 ffn2 parts)  (bias b2 already in part kc==0)
__global__ __launch_bounds__(NT) void ln3red(const float* __restrict__ f2p,
    const float* __restrict__ g3, const float* __restrict__ bb3,
    float* __restrict__ x) {
  __shared__ float sR[Dm], red[8];
  const int b = blockIdx.x, tid = threadIdx.x;
  for (int t = tid; t < Dm; t += NT) {
    const int o = (b << 9) + t;
    float v = x[o];
#pragma unroll
    for (int kc = 0; kc < 8; ++kc) v += f2p[kc * 16384 + o];
    sR[t] = v;
  }
  __syncthreads();
  block_ln(sR, g3, bb3, red);
  __syncthreads();
  for (int t = tid; t < Dm; t += NT) x[(b << 9) + t] = sR[t];
}

__global__ __launch_bounds__(512) void src_kernel(const int* __restrict__ meanings,
                                                  const float* __restrict__ emb,
                                                  float* __restrict__ src) {
  const int b = blockIdx.x, t = threadIdx.x;
  float s = 0.f;
#pragma unroll
  for (int ty = 0; ty < 8; ++ty) {
    const int idx = meanings[b * 8 + ty] + ty * 32;
    s += emb[(size_t)idx * Dm + t];
  }
  src[b * Dm + t] = s;
}

__global__ __launch_bounds__(512) void embed0(const float* __restrict__ v2e,
                                              float* __restrict__ x) {
  const int b = blockIdx.x, t = threadIdx.x;
  x[(b << 9) + t] = v2e[(size_t)(V1 - 1) * Dm + t] + pe_val(0, t);
}

// reduce 2 logits parts -> final rows, row 8192, argmax, next-token embed
__global__ __launch_bounds__(NT) void argmax_embed(float* __restrict__ x,
    const float* __restrict__ e2v_w, const float* __restrict__ e2v_b,
    const float* __restrict__ v2e, const float* __restrict__ lp,
    float* __restrict__ outLogits, float* __restrict__ outToks, int i) {
  __shared__ float red[8];
  __shared__ float sv[NT];
  __shared__ int   si[NT];
  const int b = blockIdx.x, tid = threadIdx.x, lane = tid & 63, wave = tid >> 6;
  float ls = 0.f;
  for (int t = tid; t < Dm; t += NT) ls += x[(b << 9) + t] * e2v_w[(size_t)8192 * Dm + t];
  ls = wred(ls);
  if (lane == 0) red[wave] = ls;
  __syncthreads();
  float* row = outLogits + ((size_t)i * Bn + b) * V1;
  if (tid == 0) {
    const float lg = red[0] + red[1] + red[2] + red[3] + e2v_b[8192];
    row[8192] = lg;
    red[4] = lg;
  }
  __syncthreads();
  const float lg = red[4];
  float best = -1e30f; int bi = 0;
  for (int v = tid; v < 8192; v += NT) {
    const float val = lp[(b << 13) + v] + lp[262144 + (b << 13) + v];
    row[v] = val;
    if (val > best) { best = val; bi = v; }  // strided ascending keeps first max
  }
  sv[tid] = best; si[tid] = bi;
  __syncthreads();
  for (int off = 128; off; off >>= 1) {
    if (tid < off) {
      const float v2 = sv[tid + off]; const int i2 = si[tid + off];
      if (v2 > sv[tid] || (v2 == sv[tid] && i2 < si[tid])) { sv[tid] = v2; si[tid] = i2; }
    }
    __syncthreads();
  }
  if (tid == 0) {
    int tok = si[0];
    if (lg > sv[0]) tok = 8192;  // last index wins only on strictly greater
    outToks[i * Bn + b] = (float)tok;
    si[0] = tok;
  }
  __syncthreads();
  const int tok = si[0];
  if (i + 1 < Lq) {
    for (int t = tid; t < Dm; t += NT)
      x[(b << 9) + t] = v2e[(size_t)tok * Dm + t] + pe_val(i + 1, t);
  }
}

}  // namespace

extern "C" void kernel_launch(void* const* d_in, const int* in_sizes, int n_in,
                              void* d_out, int out_size, void* d_ws, size_t ws_size,
                              hipStream_t stream) {
  (void)in_sizes; (void)n_in; (void)out_size; (void)ws_size;
  const int*   meanings  = (const int*)d_in[0];
  const float* emb_table = (const float*)d_in[1];
  const float* v2e_w     = (const float*)d_in[2];
  const float* e2v_w     = (const float*)d_in[3];
  const float* e2v_b     = (const float*)d_in[4];
  const float* sa_qkv_w  = (const float*)d_in[5];
  const float* sa_qkv_b  = (const float*)d_in[6];
  const float* sa_out_w  = (const float*)d_in[7];
  const float* sa_out_b  = (const float*)d_in[8];
  const float* ca_qkv_w  = (const float*)d_in[9];
  const float* ca_qkv_b  = (const float*)d_in[10];
  const float* ca_out_w  = (const float*)d_in[11];
  const float* ca_out_b  = (const float*)d_in[12];
  const float* ffn_w1    = (const float*)d_in[13];
  const float* ffn_b1    = (const float*)d_in[14];
  const float* ffn_w2    = (const float*)d_in[15];
  const float* ffn_b2    = (const float*)d_in[16];
  const float* ln1_g     = (const float*)d_in[17];
  const float* ln1_b     = (const float*)d_in[18];
  const float* ln2_g     = (const float*)d_in[19];
  const float* ln2_b     = (const float*)d_in[20];
  const float* ln3_g     = (const float*)d_in[21];
  const float* ln3_b     = (const float*)d_in[22];

  float* out = (float*)d_out;            // toks [16,32] then logits [16,32,8193]
  float* outLogits = out + Lq * Bn;

  float* f = (float*)d_ws;
  float* src  = f;  f += 16384;          // [32][512]
  float* x    = f;  f += 16384;          // [32][512]
  float* aout = f;  f += 16384;          // [32][512]
  float* caCp = f;  f += 131072;         // [NL][4][32][512]
  float* regA = f;  f += 655360;         // union region (per-step partials)
  float* kcache = f; f += 524288;        // [NL][16][32][512]
  float* vcache = f;
  float* qkvp = regA;                    // [3][4][32][512] = 196608
  float* sop  = regA + 196608;           // [4][32][512]    = 65536
  float* h1p  = regA + 262144;           // [4][32][2048]   = 262144
  float* f2p  = regA + 524288;           // [8][32][512]    = 131072
  float* lp   = regA;                    // [2][32][8192]   = 524288 (aliases dead bufs)

  src_kernel<<<Bn, 512, 0, stream>>>(meanings, emb_table, src);

  // cross-attn constants (memory len 1): caCp[l] parts of Wo@(Wv src + bv) + bo
  for (int l = 0; l < NL; ++l) {
    fg_part<4, 128, 1, false><<<64, NT, 0, stream>>>(src, Dm, 0,
        ca_qkv_w + ((size_t)l * 3 + 2) * Dm * Dm, Dm,
        ca_qkv_b + l * 3 * Dm + 2 * Dm, sop, Dm);
    fg_part<4, 128, 4, false><<<64, NT, 0, stream>>>(sop, Dm, 16384,
        ca_out_w + (size_t)l * Dm * Dm, Dm,
        ca_out_b + l * Dm, caCp + (size_t)l * 65536, Dm);
  }

  embed0<<<Bn, 512, 0, stream>>>(v2e_w, x);

  for (int i = 0; i < Lq; ++i) {
    for (int l = 0; l < NL; ++l) {
      float* kcl = kcache + (size_t)l * Lq * Bn * Dm;
      float* vcl = vcache + (size_t)l * Lq * Bn * Dm;
      fg_qkv_part<<<192, NT, 0, stream>>>(x,
          sa_qkv_w + (size_t)l * 3 * Dm * Dm, sa_qkv_b + l * 3 * Dm, qkvp);
      attn_core<<<Bn, NT, 0, stream>>>(qkvp, kcl, vcl, aout, i);
      fg_part<4, 128, 1, false><<<64, NT, 0, stream>>>(aout, Dm, 0,
          sa_out_w + (size_t)l * Dm * Dm, Dm, sa_out_b + l * Dm, sop, Dm);
      ln12<<<Bn, NT, 0, stream>>>(sop, caCp + (size_t)l * 65536,
          ln1_g + l * Dm, ln1_b + l * Dm, ln2_g + l * Dm, ln2_b + l * Dm, x);
      fg_part<4, 128, 1, false><<<256, NT, 0, stream>>>(x, Dm, 0,
          ffn_w1 + (size_t)l * DFF * Dm, Dm, ffn_b1 + l * DFF, h1p, DFF);
      fg_part<8, 256, 4, true><<<128, NT, 0, stream>>>(h1p, DFF, 65536,
          ffn_w2 + (size_t)l * Dm * DFF, DFF, ffn_b2 + l * Dm, f2p, Dm);
      ln3red<<<Bn, NT, 0, stream>>>(f2p,
          ln3_g + l * Dm, ln3_b + l * Dm, x);
    }
    fg_part<2, 256, 1, false><<<512, NT, 0, stream>>>(x, Dm, 0,
        e2v_w, Dm, e2v_b, lp, 8192);
    argmax_embed<<<Bn, NT, 0, stream>>>(x, e2v_w, e2v_b, v2e_w,
        lp, outLogits, out, i);
  }
}